// Round 10
// baseline (38.521 us; speedup 1.0000x reference)
//
#include <hip/hip_runtime.h>
#include <math.h>

// BrownianKernelLayer: K[i,j] = 0.5 * sum_d (|x_id|^p + |X2_jd|^p - |x_id - X2_jd|^p)
// p = 2 * softplus(log_H).  N=M=2048, D=16, fp32 in/out.
//
// v10: ZERO trans / ZERO cvt / ZERO gather in the inner loop. All full-rate.
//   log2|u|: bit-split. hif = as_float(0x4B000000 | (bits>>8 & 0x7FFFFF))
//            = 2^23 + (bits_abs>>8)  (sign bit excluded by the field select).
//            log2|u| ~= hif*2^-15... folded:  arg+192 = hif*PB + Q(mm),
//            PB = p*2^-15, Q = deg-4 runtime Chebyshev fit of p*phi(m),
//            constants -127p, +192, -256p folded into q0.
//   exp2:    t = arg+192 in [128,256) -> bits(t) encode floor/frac directly:
//            scale = as_float(((bt<<7)&0xFF800000) - 0x60800000)  (= 2^floor)
//            w     = as_float(((bt<<7)&0x007FFF80) | 0x3F800000)  (= 1+frac)
//            2^frac = deg-4 runtime-fitted poly in w; acc += scale*poly.
//            clamp t>=128 (v_max) handles u~0 -> 2^-64 ~ 0 (exact-0 correct).
// ~16 full-rate instr/term (pk-packed where possible) vs v9's 1.5V+2trans.

#define D_DIM 16
#define BR 64   // rows per tile (x)
#define BC 32   // cols per tile (X2)

typedef float v2f __attribute__((ext_vector_type(2)));

__device__ __forceinline__ float powp(float t, float p) {
    return __builtin_amdgcn_exp2f(p * __builtin_amdgcn_logf(t));
}

__global__ __launch_bounds__(256) void fbm_kernel(
    const float* __restrict__ x,    // [N, 16]
    const float* __restrict__ X2,   // [M, 16]
    const float* __restrict__ logH, // [1]
    float* __restrict__ out,        // [N, M]
    int N, int M)
{
    __shared__ float xs[D_DIM][BR];   // transposed x tile
    __shared__ float ys[D_DIM][BC];   // transposed X2 tile
    __shared__ float t1s[BR];
    __shared__ float t2s[BC];

    const int tid  = threadIdx.x;
    const int brow = blockIdx.y * BR;
    const int bcol = blockIdx.x * BC;

    const float H = log1pf(expf(logH[0]));  // softplus(log_H)
    const float p = 2.0f * H;

    // ---- deg-4 Chebyshev fit #1: phi(m) = log2(m) - (m-1) on [1,2]
    const float T1 = 0.475528258f, T2 = 0.293892626f;
    const float n0 = 1.5f + T1, n1 = 1.5f + T2, n2 = 1.5f,
                n3 = 1.5f - T2, n4 = 1.5f - T1;
    float q4, q3, q2, q1, q0;
    {
        float f0 = __builtin_amdgcn_logf(n0) - (n0 - 1.0f);
        float f1 = __builtin_amdgcn_logf(n1) - (n1 - 1.0f);
        float f2 = __builtin_amdgcn_logf(n2) - (n2 - 1.0f);
        float f3 = __builtin_amdgcn_logf(n3) - (n3 - 1.0f);
        float f4 = __builtin_amdgcn_logf(n4) - (n4 - 1.0f);
        float s1 = 0.5f * (f0 + f4), d1 = 0.5f * (f0 - f4);
        float s2 = 0.5f * (f1 + f3), d2 = 0.5f * (f1 - f3);
        float u1 = T1 * T1, u2 = T2 * T2;
        float A = s1 - f2, B = s2 - f2;
        float det = u1 * u2 * (u2 - u1);
        float e1 = (A * u2 * u2 - B * u1 * u1) / det;
        float e2 = (B * u1 - A * u2) / det;
        float Ap = d1 / T1, Bp = d2 / T2;
        float o1 = (Ap - Bp) / (u1 - u2);
        float o0 = Ap - o1 * u1;
        float a4 = e2;
        float a3 = o1 - 6.0f * e2;
        float a2 = e1 - 4.5f * o1 + 13.5f * e2;
        float a1 = o0 - 3.0f * e1 + 6.75f * o1 - 13.5f * e2;
        float a0 = f2 - 1.5f * o0 + 2.25f * e1 - 3.375f * o1 + 5.0625f * e2;
        q4 = p * a4; q3 = p * a3; q2 = p * a2; q1 = p * a1;
        // fold: -127p (bias), +192 (range shift), -256p (hif's 2^23*PB term)
        q0 = p * a0 - 383.0f * p + 192.0f;
    }
    const float PB = p * (1.0f / 32768.0f);   // p * 2^-15

    // ---- deg-4 Chebyshev fit #2: g(w) = 2^(w-1) on [1,2] (same nodes)
    float e4c, e3c, e2c, e1c, e0c;
    {
        float f0 = __builtin_amdgcn_exp2f(n0 - 1.0f);
        float f1 = __builtin_amdgcn_exp2f(n1 - 1.0f);
        float f2 = __builtin_amdgcn_exp2f(n2 - 1.0f);
        float f3 = __builtin_amdgcn_exp2f(n3 - 1.0f);
        float f4 = __builtin_amdgcn_exp2f(n4 - 1.0f);
        float s1 = 0.5f * (f0 + f4), d1 = 0.5f * (f0 - f4);
        float s2 = 0.5f * (f1 + f3), d2 = 0.5f * (f1 - f3);
        float u1 = T1 * T1, u2 = T2 * T2;
        float A = s1 - f2, B = s2 - f2;
        float det = u1 * u2 * (u2 - u1);
        float ee1 = (A * u2 * u2 - B * u1 * u1) / det;
        float ee2 = (B * u1 - A * u2) / det;
        float Ap = d1 / T1, Bp = d2 / T2;
        float oo1 = (Ap - Bp) / (u1 - u2);
        float oo0 = Ap - oo1 * u1;
        e4c = ee2;
        e3c = oo1 - 6.0f * ee2;
        e2c = ee1 - 4.5f * oo1 + 13.5f * ee2;
        e1c = oo0 - 3.0f * ee1 + 6.75f * oo1 - 13.5f * ee2;
        e0c = f2 - 1.5f * oo0 + 2.25f * ee1 - 3.375f * oo1 + 5.0625f * ee2;
    }

    // ---- stage x tile: 64 rows x 16 d = 1024 floats = 256 x float4
    {
        float4 vx = ((const float4*)(x + (size_t)brow * D_DIM))[tid];
        int r  = tid >> 2;
        int d0 = (tid & 3) << 2;
        xs[d0 + 0][r] = vx.x; xs[d0 + 1][r] = vx.y;
        xs[d0 + 2][r] = vx.z; xs[d0 + 3][r] = vx.w;
    }
    // ---- stage X2 tile: 32 rows x 16 d = 512 floats = 128 x float4
    if (tid < 128) {
        float4 vy = ((const float4*)(X2 + (size_t)bcol * D_DIM))[tid];
        int r  = tid >> 2;
        int d0 = (tid & 3) << 2;
        ys[d0 + 0][r] = vy.x; ys[d0 + 1][r] = vy.y;
        ys[d0 + 2][r] = vy.z; ys[d0 + 3][r] = vy.w;
    }
    __syncthreads();

    // ---- per-row self terms (exact trans path; negligible count)
    if (tid < BR) {
        float s = 0.0f;
        #pragma unroll
        for (int d = 0; d < D_DIM; ++d) s += powp(fabsf(xs[d][tid]), p);
        t1s[tid] = s;
    } else if (tid < BR + BC) {
        int r = tid - BR;
        float s = 0.0f;
        #pragma unroll
        for (int d = 0; d < D_DIM; ++d) s += powp(fabsf(ys[d][r]), p);
        t2s[r] = s;
    }
    __syncthreads();

    // ---- main: 4x2 outputs per thread; 16x16 thread grid covers 64x32
    const int ti = tid >> 4;
    const int tj = tid & 15;

    v2f acc2[4] = {};

    #pragma unroll 4
    for (int d = 0; d < D_DIM; ++d) {
        float4 xa = *(const float4*)&xs[d][ti * 4];
        v2f bv = *(const v2f*)&ys[d][tj * 2];
        float A0 = xa.x, A1 = xa.y, A2 = xa.z, A3 = xa.w;

        #define TERM2(A_, IDX_) { \
            v2f av_; av_.x = (A_); av_.y = (A_); \
            v2f u_ = av_ - bv;                                   /* pk */ \
            unsigned b0_ = __float_as_uint(u_.x); \
            unsigned b1_ = __float_as_uint(u_.y); \
            v2f hif_; \
            hif_.x = __uint_as_float(0x4B000000u | ((b0_ >> 8) & 0x007FFFFFu)); \
            hif_.y = __uint_as_float(0x4B000000u | ((b1_ >> 8) & 0x007FFFFFu)); \
            v2f mm_; \
            mm_.x = __uint_as_float((b0_ & 0x007FFFFFu) | 0x3F800000u); \
            mm_.y = __uint_as_float((b1_ & 0x007FFFFFu) | 0x3F800000u); \
            v2f t_ = q4; \
            t_ = t_ * mm_ + q3; \
            t_ = t_ * mm_ + q2; \
            t_ = t_ * mm_ + q1; \
            t_ = t_ * mm_ + q0; \
            t_ = hif_ * PB + t_;                                 /* = arg+192 */ \
            t_.x = fmaxf(t_.x, 128.0f); \
            t_.y = fmaxf(t_.y, 128.0f); \
            unsigned bt0_ = __float_as_uint(t_.x) << 7; \
            unsigned bt1_ = __float_as_uint(t_.y) << 7; \
            v2f sc_; \
            sc_.x = __uint_as_float((bt0_ & 0xFF800000u) - 0x60800000u); \
            sc_.y = __uint_as_float((bt1_ & 0xFF800000u) - 0x60800000u); \
            v2f w_; \
            w_.x = __uint_as_float((bt0_ & 0x007FFF80u) | 0x3F800000u); \
            w_.y = __uint_as_float((bt1_ & 0x007FFF80u) | 0x3F800000u); \
            v2f g_ = e4c; \
            g_ = g_ * w_ + e3c; \
            g_ = g_ * w_ + e2c; \
            g_ = g_ * w_ + e1c; \
            g_ = g_ * w_ + e0c; \
            acc2[IDX_] += sc_ * g_; }

        TERM2(A0, 0)
        TERM2(A1, 1)
        TERM2(A2, 2)
        TERM2(A3, 3)
        #undef TERM2
    }

    // ---- epilogue: K = 0.5*(t1[i] + t2[j] - t3)
    float t2v0 = t2s[tj * 2 + 0];
    float t2v1 = t2s[tj * 2 + 1];

    #pragma unroll
    for (int a = 0; a < 4; ++a) {
        float t1v = t1s[ti * 4 + a];
        float2 o;
        o.x = 0.5f * (t1v + t2v0 - acc2[a].x);
        o.y = 0.5f * (t1v + t2v1 - acc2[a].y);
        int gi = brow + ti * 4 + a;
        *(float2*)(out + (size_t)gi * M + bcol + tj * 2) = o;
    }
}

extern "C" void kernel_launch(void* const* d_in, const int* in_sizes, int n_in,
                              void* d_out, int out_size, void* d_ws, size_t ws_size,
                              hipStream_t stream) {
    const float* x    = (const float*)d_in[0];
    const float* X2   = (const float*)d_in[1];
    const float* logH = (const float*)d_in[2];
    float* out = (float*)d_out;

    int N = in_sizes[0] / D_DIM;
    int M = in_sizes[1] / D_DIM;

    dim3 grid(M / BC, N / BR);
    dim3 block(256);
    fbm_kernel<<<grid, block, 0, stream>>>(x, X2, logH, out, N, M);
}

// Round 11
// 20.654 us; speedup vs baseline: 1.8650x; 1.8650x over previous
//
#include <hip/hip_runtime.h>
#include <math.h>

// BrownianKernelLayer: K[i,j] = 0.5 * sum_d (|x_id|^p + |X2_jd|^p - |x_id - X2_jd|^p)
// p = 2 * softplus(log_H).  N=M=2048, D=16, fp32 in/out.
//
// v11 = v9 (best: 21.5us; per 2 terms: pk_sub + 2 v_log + pk_mul + 2 v_exp +
// pk_add — measured-irreducible: trans ops ~6cyc, emulation costs 2-4x more)
// with the 64x64 tile / 4x4 micro-tile of v2 (occupancy-neutral, proven) so
// each pair of ds_read_b128 feeds 16 terms instead of 8 — halves LDS/loop
// overhead per term. Model: ~15 cyc/term trans-issue floor at the throttled
// (~1.1-1.3 GHz sustained, per v10's VALUBusy=72% @ 28 VGPR) clock.

#define D_DIM 16
#define BLK 64

typedef float v2f __attribute__((ext_vector_type(2)));

__device__ __forceinline__ float powp(float t, float p) {
    return __builtin_amdgcn_exp2f(p * __builtin_amdgcn_logf(t));
}

__global__ __launch_bounds__(256) void fbm_kernel(
    const float* __restrict__ x,    // [N, 16]
    const float* __restrict__ X2,   // [M, 16]
    const float* __restrict__ logH, // [1]
    float* __restrict__ out,        // [N, M]
    int N, int M)
{
    __shared__ float xs[D_DIM][BLK];   // transposed x tile
    __shared__ float ys[D_DIM][BLK];   // transposed X2 tile
    __shared__ float t1s[BLK];
    __shared__ float t2s[BLK];

    const int tid  = threadIdx.x;
    const int brow = blockIdx.y * BLK;
    const int bcol = blockIdx.x * BLK;

    const float p = 2.0f * log1pf(expf(logH[0]));  // 2*softplus

    // ---- stage: 64 rows x 16 d = 1024 floats per tile = 256 threads x float4
    {
        float4 vx = ((const float4*)(x  + (size_t)brow * D_DIM))[tid];
        float4 vy = ((const float4*)(X2 + (size_t)bcol * D_DIM))[tid];
        int r  = tid >> 2;
        int d0 = (tid & 3) << 2;
        xs[d0 + 0][r] = vx.x; xs[d0 + 1][r] = vx.y;
        xs[d0 + 2][r] = vx.z; xs[d0 + 3][r] = vx.w;
        ys[d0 + 0][r] = vy.x; ys[d0 + 1][r] = vy.y;
        ys[d0 + 2][r] = vy.z; ys[d0 + 3][r] = vy.w;
    }
    __syncthreads();

    // ---- per-row self terms t1 (x rows) / t2 (X2 rows)
    if (tid < 128) {
        int r = tid & 63;
        const float (*src)[BLK] = (tid < 64) ? xs : ys;
        float s = 0.0f;
        #pragma unroll
        for (int d = 0; d < D_DIM; ++d) s += powp(fabsf(src[d][r]), p);
        if (tid < 64) t1s[r] = s; else t2s[r] = s;
    }
    __syncthreads();

    // ---- main: 4x4 outputs per thread; 16x16 thread grid covers 64x64
    const int ti = tid >> 4;
    const int tj = tid & 15;

    const v2f pv = {p, p};
    v2f acc2[4][2] = {};   // [row][col-pair]

    #pragma unroll 4
    for (int d = 0; d < D_DIM; ++d) {
        float4 xa = *(const float4*)&xs[d][ti * 4];
        float4 xb = *(const float4*)&ys[d][tj * 4];
        v2f b01; b01.x = xb.x; b01.y = xb.y;
        v2f b23; b23.x = xb.z; b23.y = xb.w;
        float A0 = xa.x, A1 = xa.y, A2 = xa.z, A3 = xa.w;

        #define TERM2(A_, BV_, R_, C_) { \
            v2f av_; av_.x = (A_); av_.y = (A_); \
            v2f u_ = av_ - BV_;                      /* v_pk_add(neg) */ \
            float l0_ = __builtin_amdgcn_logf(__builtin_fabsf(u_.x)); \
            float l1_ = __builtin_amdgcn_logf(__builtin_fabsf(u_.y)); \
            v2f lv_; lv_.x = l0_; lv_.y = l1_; \
            lv_ = lv_ * pv;                          /* v_pk_mul */ \
            float e0_ = __builtin_amdgcn_exp2f(lv_.x); \
            float e1_ = __builtin_amdgcn_exp2f(lv_.y); \
            v2f ev_; ev_.x = e0_; ev_.y = e1_; \
            acc2[R_][C_] += ev_; }                   /* v_pk_add */

        TERM2(A0, b01, 0, 0) TERM2(A0, b23, 0, 1)
        TERM2(A1, b01, 1, 0) TERM2(A1, b23, 1, 1)
        TERM2(A2, b01, 2, 0) TERM2(A2, b23, 2, 1)
        TERM2(A3, b01, 3, 0) TERM2(A3, b23, 3, 1)
        #undef TERM2
    }

    // ---- epilogue: K = 0.5*(t1[i] + t2[j] - t3)
    float t2v0 = t2s[tj * 4 + 0];
    float t2v1 = t2s[tj * 4 + 1];
    float t2v2 = t2s[tj * 4 + 2];
    float t2v3 = t2s[tj * 4 + 3];

    #pragma unroll
    for (int a = 0; a < 4; ++a) {
        float t1v = t1s[ti * 4 + a];
        float4 o;
        o.x = 0.5f * (t1v + t2v0 - acc2[a][0].x);
        o.y = 0.5f * (t1v + t2v1 - acc2[a][0].y);
        o.z = 0.5f * (t1v + t2v2 - acc2[a][1].x);
        o.w = 0.5f * (t1v + t2v3 - acc2[a][1].y);
        int gi = brow + ti * 4 + a;
        *(float4*)(out + (size_t)gi * M + bcol + tj * 4) = o;
    }
}

extern "C" void kernel_launch(void* const* d_in, const int* in_sizes, int n_in,
                              void* d_out, int out_size, void* d_ws, size_t ws_size,
                              hipStream_t stream) {
    const float* x    = (const float*)d_in[0];
    const float* X2   = (const float*)d_in[1];
    const float* logH = (const float*)d_in[2];
    float* out = (float*)d_out;

    int N = in_sizes[0] / D_DIM;
    int M = in_sizes[1] / D_DIM;

    dim3 grid(M / BLK, N / BLK);
    dim3 block(256);
    fbm_kernel<<<grid, block, 0, stream>>>(x, X2, logH, out, N, M);
}